// Round 13
// baseline (1128.276 us; speedup 1.0000x reference)
//
#include <hip/hip_runtime.h>
#include <math.h>

// ---------------------------------------------------------------------------
// GCN summarizer: 4x (GEMM 128x128 -> normalized-adjacency aggregate + bias
// + relu) -> segmented mean-pool -> dot Wc -> sigmoid.
// R13: R10 base (best: 64-thr 2-node aggregates, standalone 4-VGPR edge_pass)
//      + tbuf stored as per-row-scaled LINEAR INT4 (64 B/row -> half the
//      random-fill traffic). Decode = bfe+cvt (2 VALU/nibble, no LUT/LDS);
//      encode = mul+rint+pack in GEMM epilogue; per-row scale via SGPR loads.
//      hbuf bf16 (kappa), fp32 accumulate.
// ---------------------------------------------------------------------------

#define MASK40 ((1ull << 40) - 1)

typedef __bf16 bf16x8 __attribute__((ext_vector_type(8)));
typedef float f32x4 __attribute__((ext_vector_type(4)));

__device__ inline unsigned f2bf(float x) {            // round-to-nearest-even
    unsigned u = __float_as_uint(x);
    return (u + 0x7FFFu + ((u >> 16) & 1u)) >> 16;
}

// signed 4-bit field k of u -> float  (v_bfe_i32 + v_cvt_f32_i32)
__device__ inline float dec4(unsigned u, int k) {
    int v = ((int)(u << (28 - 4 * k))) >> 28;
    return (float)v;
}

// one u64 atomic per edge: high 24 bits = count, low 40 = sum(ew) in 2^-24 fx.
// returned old value gives this edge's rank among same-dst edges -> slot[e].
// Standalone thin kernel (4 VGPR) -> max occupancy for atomics in flight.
__global__ void edge_pass(const int* __restrict__ dst, const float* __restrict__ ew,
                          unsigned long long* packed, unsigned short* __restrict__ slot,
                          int E) {
    int e = blockIdx.x * blockDim.x + threadIdx.x;
    if (e < E) {
        int d = dst[e];
        unsigned int fx = (unsigned int)rintf(ew[e] * 16777216.0f);
        unsigned long long old =
            atomicAdd(&packed[d], (1ull << 40) | (unsigned long long)fx);
        slot[e] = (unsigned short)(old >> 40);
    }
}

// exclusive scan over L[i] = cnt[i]+1, fused with dinv computation.
__global__ __launch_bounds__(1024) void scan1(const unsigned long long* __restrict__ packed,
                                              float* __restrict__ dinv, int* rowp,
                                              int* bsums, int total, int N) {
    __shared__ int sh[1024];
    int i = blockIdx.x * 1024 + threadIdx.x;
    int v = 0;
    if (i < N) {
        unsigned long long p = packed[i];
        float deg = 1.0f + (float)(p & MASK40) * (1.0f / 16777216.0f);
        dinv[i] = rsqrtf(deg);
        v = (int)(p >> 40) + 1;
    }
    sh[threadIdx.x] = v;
    __syncthreads();
    for (int off = 1; off < 1024; off <<= 1) {
        int t = (threadIdx.x >= (unsigned)off) ? sh[threadIdx.x - off] : 0;
        __syncthreads();
        sh[threadIdx.x] += t;
        __syncthreads();
    }
    if (i < total) rowp[i] = sh[threadIdx.x] - v;      // exclusive, pre-offset
    if (threadIdx.x == 1023) bsums[blockIdx.x] = sh[1023];
}

__global__ void scan2(int* bsums, int nb) {
    if (threadIdx.x == 0 && blockIdx.x == 0) {
        int run = 0;
        for (int b = 0; b < nb; ++b) { int t = bsums[b]; bsums[b] = run; run += t; }
    }
}

__global__ __launch_bounds__(1024) void scan3(int* rowp, const int* __restrict__ bsums,
                                              int total) {
    int i = blockIdx.x * 1024 + threadIdx.x;
    if (i < total) rowp[i] += bsums[blockIdx.x];
}

__global__ void selfloop_k(const int* __restrict__ rowp, const float* __restrict__ dinv,
                           int2* colval, int n) {
    int i = blockIdx.x * blockDim.x + threadIdx.x;
    if (i < n) {
        float dv = dinv[i];
        int2 cv;
        cv.x = i;
        cv.y = __float_as_int(dv * dv);   // dinv[i] * 1.0 * dinv[i]
        colval[rowp[i]] = cv;
    }
}

// atomic-free scatter: one 8-B write per edge (col+val interleaved).
__global__ void scatter2(const int* __restrict__ src, const int* __restrict__ dst,
                         const float* __restrict__ ew,
                         const unsigned short* __restrict__ slot,
                         const float* __restrict__ dinv, const int* __restrict__ rowp,
                         int2* colval, int E) {
    int e = blockIdx.x * blockDim.x + threadIdx.x;
    if (e < E) {
        int s = src[e], d = dst[e];
        int idx = rowp[d] + 1 + (int)slot[e];
        int2 cv;
        cv.x = s;
        cv.y = __float_as_int(dinv[s] * ew[e] * dinv[d]);
        colval[idx] = cv;
    }
}

// start[g] = lower_bound(batch, g) for g in [0, G]; batch is sorted.
__global__ void gstart_k(const int* __restrict__ batch, int* start, int N, int G) {
    int g = blockIdx.x * blockDim.x + threadIdx.x;
    if (g <= G) {
        int lo = 0, hi = N;
        while (lo < hi) {
            int mid = (lo + hi) >> 1;
            if (batch[mid] < g) lo = mid + 1; else hi = mid;
        }
        start[g] = lo;
    }
}

// Wt[l][c*128 + p] = bf16( W_l[ kappa_l(p) ][ c ] ); kappa_1 = identity,
// kappa_{2,3,4}(p): t=p>>1,h=p&1 -> k = 16*(4*((t>>1)&1)+2*(t&1)+h) + (t>>2).
__global__ void prep_w(const float* __restrict__ Wa, const float* __restrict__ Wb,
                       const float* __restrict__ Wc, const float* __restrict__ Wd,
                       unsigned short* __restrict__ Wt) {
    const int l = blockIdx.y;
    const float* W = (l == 0) ? Wa : (l == 1) ? Wb : (l == 2) ? Wc : Wd;
    const int c = blockIdx.x, p = threadIdx.x;
    int k;
    if (l == 0) {
        k = p;
    } else {
        int t = p >> 1, h = p & 1;
        int i = t >> 2, s = (t >> 1) & 1, jj = 2 * (t & 1) + h;
        k = 16 * (4 * s + jj) + i;
    }
    float v = W[k * 128 + c];
    unsigned u = __float_as_uint(v);
    Wt[l * 16384 + c * 128 + p] = (unsigned short)((u + 0x7FFFu + ((u >> 16) & 1u)) >> 16);
}

// ---------------------------------------------------------------------------
// MFMA GEMM: C = A @ W. A: fp32 (layer 1, natural order) or packed-bf16 rows
// (kappa order). Wt: bf16 [col][k] (32 KB, L1-resident). C: linear-int4 rows
// (16 uints = 64 B) + sc[row] = amax/7. Block 256 thr = 4 waves; wave owns
// 16 rows x 128 cols. C/D: col=ct*16+li, row=q*4+reg.
// uint li of a row holds nibble ct = quant(feat 16*ct+li).
// ---------------------------------------------------------------------------
template <int FP32IN>
__global__ __launch_bounds__(256) void gemm_mfma(const void* __restrict__ Av,
                                                 const uint4* __restrict__ Wt,
                                                 unsigned* __restrict__ C4,
                                                 float* __restrict__ sc, int N) {
    const int w = threadIdx.x >> 6;
    const int lane = threadIdx.x & 63;
    const int li = lane & 15, q = lane >> 4;
    const long row_base = (long)blockIdx.x * 64 + w * 16;
    const long arow = (row_base + li < (long)N) ? row_base + li : (long)N - 1;

    f32x4 acc[8];
#pragma unroll
    for (int t = 0; t < 8; ++t) acc[t] = (f32x4){0.f, 0.f, 0.f, 0.f};

#pragma unroll
    for (int ks = 0; ks < 4; ++ks) {
        bf16x8 af;
        if (FP32IN) {
            const float* Ar = (const float*)Av + arow * 128 + ks * 32 + q * 8;
            const float4 fa = *(const float4*)Ar;
            const float4 fb = *(const float4*)(Ar + 4);
            uint4 u;
            u.x = f2bf(fa.x) | (f2bf(fa.y) << 16);
            u.y = f2bf(fa.z) | (f2bf(fa.w) << 16);
            u.z = f2bf(fb.x) | (f2bf(fb.y) << 16);
            u.w = f2bf(fb.z) | (f2bf(fb.w) << 16);
            af = __builtin_bit_cast(bf16x8, u);
        } else {
            af = __builtin_bit_cast(bf16x8,
                ((const uint4*)Av)[arow * 16 + ks * 4 + q]);
        }
#pragma unroll
        for (int ct = 0; ct < 8; ++ct) {
            const bf16x8 bf = __builtin_bit_cast(
                bf16x8, Wt[(size_t)(ct * 16 + li) * 16 + ks * 4 + q]);
            acc[ct] = __builtin_amdgcn_mfma_f32_16x16x32_bf16(af, bf, acc[ct], 0, 0, 0);
        }
    }

#pragma unroll
    for (int reg = 0; reg < 4; ++reg) {
        float amax = 0.f;
#pragma unroll
        for (int ct = 0; ct < 8; ++ct) amax = fmaxf(amax, fabsf(acc[ct][reg]));
#pragma unroll
        for (int m = 1; m < 16; m <<= 1) amax = fmaxf(amax, __shfl_xor(amax, m));
        const float qs = (amax > 0.f) ? 7.0f / amax : 0.f;
        const long row = row_base + q * 4 + reg;
        if (li == 0) sc[row] = amax * (1.0f / 7.0f);
        unsigned u = 0;
#pragma unroll
        for (int ct = 0; ct < 8; ++ct) {
            const int v = (int)rintf(acc[ct][reg] * qs);
            u |= ((unsigned)v & 15u) << (ct * 4);
        }
        C4[row * 16 + li] = u;
    }
}

// ---------------------------------------------------------------------------
// Aggregate, 2 nodes per 64-lane wave (one wave per block -> blockIdx-derived
// indices are provably uniform -> rowp/colval/sc all on the scalar pipe).
// Half h = lane>>5 handles node v0+h; lane il = lane&31 loads one ushort
// (4 int4 feats; f0 = 64*(il&1)+(il>>1), feats f0+16j). Decode = bfe+cvt.
// w=0 past the short half's end. fp32 acc; writes packed-bf16 (kappa order).
// ---------------------------------------------------------------------------
__global__ __launch_bounds__(64) void aggregate2(const unsigned short* __restrict__ t16,
                                                 const float* __restrict__ sc,
                                                 const int* __restrict__ rowp,
                                                 const int2* __restrict__ colval,
                                                 const float* __restrict__ bias,
                                                 unsigned* __restrict__ out16, int n) {
    const int v0 = blockIdx.x * 2;
    const int lane = threadIdx.x;
    const int h = lane >> 5, il = lane & 31;

    const int base0 = rowp[v0];
    const int mid   = rowp[v0 + 1];
    const bool have1 = (v0 + 1) < n;
    const int end1  = have1 ? rowp[v0 + 2] : mid;
    const int len0 = mid - base0;
    const int len1 = end1 - mid;
    const int maxlen = (len0 > len1) ? len0 : len1;
    const int lenh = h ? len1 : len0;

    float a0 = 0.f, a1 = 0.f, a2 = 0.f, a3 = 0.f;
    int j = 0;
    for (; j + 4 <= maxlen; j += 4) {
#pragma unroll
        for (int k = 0; k < 4; ++k) {
            const int jj = j + k;
            const int j0 = (jj < len0) ? jj : len0 - 1;
            const int j1 = (jj < len1) ? jj : len1 - 1;
            const int2 ca = colval[base0 + j0];
            const int2 cb = colval[mid + j1];
            const float sa = sc[ca.x];          // SGPR load (ca.x uniform)
            const float sb = sc[cb.x];
            const int c = h ? cb.x : ca.x;
            float w = __int_as_float(h ? cb.y : ca.y) * (h ? sb : sa);
            w = (jj < lenh) ? w : 0.f;
            const unsigned u = t16[(size_t)c * 32 + il];
            a0 = fmaf(w, dec4(u, 0), a0);
            a1 = fmaf(w, dec4(u, 1), a1);
            a2 = fmaf(w, dec4(u, 2), a2);
            a3 = fmaf(w, dec4(u, 3), a3);
        }
    }
    for (; j < maxlen; ++j) {
        const int j0 = (j < len0) ? j : len0 - 1;
        const int j1 = (j < len1) ? j : len1 - 1;
        const int2 ca = colval[base0 + j0];
        const int2 cb = colval[mid + j1];
        const float sa = sc[ca.x];
        const float sb = sc[cb.x];
        const int c = h ? cb.x : ca.x;
        float w = __int_as_float(h ? cb.y : ca.y) * (h ? sb : sa);
        w = (j < lenh) ? w : 0.f;
        const unsigned u = t16[(size_t)c * 32 + il];
        a0 = fmaf(w, dec4(u, 0), a0);
        a1 = fmaf(w, dec4(u, 1), a1);
        a2 = fmaf(w, dec4(u, 2), a2);
        a3 = fmaf(w, dec4(u, 3), a3);
    }

    const int f0 = 64 * (il & 1) + (il >> 1);
    const float r0 = fmaxf(a0 + bias[f0],      0.f);
    const float r1 = fmaxf(a1 + bias[f0 + 16], 0.f);
    const float r2 = fmaxf(a2 + bias[f0 + 32], 0.f);
    const float r3 = fmaxf(a3 + bias[f0 + 48], 0.f);
    const int v = v0 + h;
    if (v < n) {
        uint2 o;
        o.x = f2bf(r0) | (f2bf(r1) << 16);
        o.y = f2bf(r2) | (f2bf(r3) << 16);
        *(uint2*)&out16[(size_t)v * 64 + il * 2] = o;
    }
}

// last layer: gather as above, dot with Wc + half-wave reduce -> sv[v] (4 B).
__global__ __launch_bounds__(64) void aggregate2_last(const unsigned short* __restrict__ t16,
                                                      const float* __restrict__ sc,
                                                      const int* __restrict__ rowp,
                                                      const int2* __restrict__ colval,
                                                      const float* __restrict__ bias,
                                                      const float* __restrict__ Wc,
                                                      float* __restrict__ sv, int n) {
    const int v0 = blockIdx.x * 2;
    const int lane = threadIdx.x;
    const int h = lane >> 5, il = lane & 31;

    const int base0 = rowp[v0];
    const int mid   = rowp[v0 + 1];
    const bool have1 = (v0 + 1) < n;
    const int end1  = have1 ? rowp[v0 + 2] : mid;
    const int len0 = mid - base0;
    const int len1 = end1 - mid;
    const int maxlen = (len0 > len1) ? len0 : len1;
    const int lenh = h ? len1 : len0;

    float a0 = 0.f, a1 = 0.f, a2 = 0.f, a3 = 0.f;
    int j = 0;
    for (; j + 4 <= maxlen; j += 4) {
#pragma unroll
        for (int k = 0; k < 4; ++k) {
            const int jj = j + k;
            const int j0 = (jj < len0) ? jj : len0 - 1;
            const int j1 = (jj < len1) ? jj : len1 - 1;
            const int2 ca = colval[base0 + j0];
            const int2 cb = colval[mid + j1];
            const float sa = sc[ca.x];
            const float sb = sc[cb.x];
            const int c = h ? cb.x : ca.x;
            float w = __int_as_float(h ? cb.y : ca.y) * (h ? sb : sa);
            w = (jj < lenh) ? w : 0.f;
            const unsigned u = t16[(size_t)c * 32 + il];
            a0 = fmaf(w, dec4(u, 0), a0);
            a1 = fmaf(w, dec4(u, 1), a1);
            a2 = fmaf(w, dec4(u, 2), a2);
            a3 = fmaf(w, dec4(u, 3), a3);
        }
    }
    for (; j < maxlen; ++j) {
        const int j0 = (j < len0) ? j : len0 - 1;
        const int j1 = (j < len1) ? j : len1 - 1;
        const int2 ca = colval[base0 + j0];
        const int2 cb = colval[mid + j1];
        const float sa = sc[ca.x];
        const float sb = sc[cb.x];
        const int c = h ? cb.x : ca.x;
        float w = __int_as_float(h ? cb.y : ca.y) * (h ? sb : sa);
        w = (j < lenh) ? w : 0.f;
        const unsigned u = t16[(size_t)c * 32 + il];
        a0 = fmaf(w, dec4(u, 0), a0);
        a1 = fmaf(w, dec4(u, 1), a1);
        a2 = fmaf(w, dec4(u, 2), a2);
        a3 = fmaf(w, dec4(u, 3), a3);
    }

    const int f0 = 64 * (il & 1) + (il >> 1);
    float p = fmaxf(a0 + bias[f0],      0.f) * Wc[f0]
            + fmaxf(a1 + bias[f0 + 16], 0.f) * Wc[f0 + 16]
            + fmaxf(a2 + bias[f0 + 32], 0.f) * Wc[f0 + 32]
            + fmaxf(a3 + bias[f0 + 48], 0.f) * Wc[f0 + 48];
#pragma unroll
    for (int off = 16; off; off >>= 1) p += __shfl_xor(p, off);  // within half
    const int v = v0 + h;
    if (il == 0 && v < n) sv[v] = p;
}

// one block per graph: mean of sv over the (contiguous) segment, sigmoid.
__global__ __launch_bounds__(256) void seg_pool(const float* __restrict__ sv,
                                                const int* __restrict__ start,
                                                const float* __restrict__ bc,
                                                float* __restrict__ out, int G) {
    __shared__ float sh[4];
    const int g = blockIdx.x;
    const int s = start[g], epos = start[g + 1];
    float acc = 0.f;
    for (int i = s + threadIdx.x; i < epos; i += 256) acc += sv[i];
#pragma unroll
    for (int off = 32; off; off >>= 1) acc += __shfl_down(acc, off);
    if ((threadIdx.x & 63) == 0) sh[threadIdx.x >> 6] = acc;
    __syncthreads();
    if (threadIdx.x == 0) {
        float sum = sh[0] + sh[1] + sh[2] + sh[3];
        float cnt = (float)(epos - s);
        float z = sum / fmaxf(cnt, 1.0f) + bc[0];
        out[g] = 1.0f / (1.0f + expf(-z));
    }
}

extern "C" void kernel_launch(void* const* d_in, const int* in_sizes, int n_in,
                              void* d_out, int out_size, void* d_ws, size_t ws_size,
                              hipStream_t stream) {
    const float* x   = (const float*)d_in[0];
    const int* ei    = (const int*)d_in[1];
    const float* ew  = (const float*)d_in[2];
    const int* batch = (const int*)d_in[3];
    const float* W1 = (const float*)d_in[4];  const float* b1 = (const float*)d_in[5];
    const float* W2 = (const float*)d_in[6];  const float* b2 = (const float*)d_in[7];
    const float* W3 = (const float*)d_in[8];  const float* b3 = (const float*)d_in[9];
    const float* W4 = (const float*)d_in[10]; const float* b4 = (const float*)d_in[11];
    const float* Wc = (const float*)d_in[12]; const float* bc = (const float*)d_in[13];

    const int N = in_sizes[0] / 128;
    const int E = in_sizes[2];
    const int G = out_size;
    const int* src = ei;
    const int* dst = ei + E;
    const int nblk = (N + 63) / 64;
    const long Npad = (long)nblk * 64;

    // workspace carve (re-poisoned each call; everything read is written below
    // or harmlessly finite-garbage in pad rows)
    char* p = (char*)d_ws;
    auto alloc = [&](size_t bytes) {
        void* q = (void*)p;
        p += (bytes + 255) & ~(size_t)255;
        return q;
    };
    unsigned long long* packed = (unsigned long long*)alloc((size_t)N * 8);
    float* dinv = (float*)alloc((size_t)N * 4);
    unsigned short* slot = (unsigned short*)alloc((size_t)E * 2);
    int* rowp   = (int*)alloc((size_t)(N + 1) * 4);
    int* bsums  = (int*)alloc(1024 * 4);
    const size_t M = (size_t)E + (size_t)N;
    int2* colval = (int2*)alloc(M * 8);
    unsigned* tbuf = (unsigned*)alloc((size_t)Npad * 16 * 4);  // int4 GEMM out (64 B/row)
    float* scb     = (float*)alloc((size_t)Npad * 4);          // per-row dequant scale
    unsigned* hbuf = (unsigned*)alloc((size_t)Npad * 64 * 4);  // bf16 activations
    unsigned short* Wt = (unsigned short*)alloc(4 * 16384 * 2); // bf16 Wt[4]
    float* sv   = (float*)alloc((size_t)N * 4);
    int* start  = (int*)alloc((size_t)(G + 1) * 4);

    const int B = 256;
    const uint4* Wt4 = (const uint4*)Wt;

    // --- graph normalization + CSR build (one atomic per edge total) ---
    hipMemsetAsync(packed, 0, (size_t)N * 8, stream);
    edge_pass<<<(E + B - 1) / B, B, 0, stream>>>(dst, ew, packed, slot, E);
    const int total = N + 1;
    const int nb = (total + 1023) / 1024;
    scan1<<<nb, 1024, 0, stream>>>(packed, dinv, rowp, bsums, total, N);
    scan2<<<1, 64, 0, stream>>>(bsums, nb);
    scan3<<<nb, 1024, 0, stream>>>(rowp, bsums, total);
    selfloop_k<<<(N + B - 1) / B, B, 0, stream>>>(rowp, dinv, colval, N);
    scatter2<<<(E + B - 1) / B, B, 0, stream>>>(src, dst, ew, slot, dinv, rowp,
                                                colval, E);
    gstart_k<<<(G + 1 + B - 1) / B, B, 0, stream>>>(batch, start, N, G);
    prep_w<<<dim3(128, 4), 128, 0, stream>>>(W1, W2, W3, W4, Wt);

    // --- 4 GCN layers ---
    const int agrid = (N + 1) / 2;
    const unsigned short* t16 = (const unsigned short*)tbuf;
    gemm_mfma<1><<<nblk, B, 0, stream>>>(x,    Wt4,        tbuf, scb, N);
    aggregate2<<<agrid, 64, 0, stream>>>(t16, scb, rowp, colval, b1, hbuf, N);
    gemm_mfma<0><<<nblk, B, 0, stream>>>(hbuf, Wt4 + 2048, tbuf, scb, N);
    aggregate2<<<agrid, 64, 0, stream>>>(t16, scb, rowp, colval, b2, hbuf, N);
    gemm_mfma<0><<<nblk, B, 0, stream>>>(hbuf, Wt4 + 4096, tbuf, scb, N);
    aggregate2<<<agrid, 64, 0, stream>>>(t16, scb, rowp, colval, b3, hbuf, N);
    gemm_mfma<0><<<nblk, B, 0, stream>>>(hbuf, Wt4 + 6144, tbuf, scb, N);
    aggregate2_last<<<agrid, 64, 0, stream>>>(t16, scb, rowp, colval, b4, Wc, sv, N);

    // --- segmented mean pool (batch sorted) + sigmoid ---
    seg_pool<<<G, B, 0, stream>>>(sv, start, bc, (float*)d_out, G);
}

// Round 14
// 789.287 us; speedup vs baseline: 1.4295x; 1.4295x over previous
//
#include <hip/hip_runtime.h>
#include <math.h>

// ---------------------------------------------------------------------------
// GCN summarizer: 4x (GEMM 128x128 -> normalized-adjacency aggregate + bias
// + relu) -> segmented mean-pool -> dot Wc -> sigmoid.
// R14: R10 config restored (fp8-e4m3 gather w/ HW cvt — R9/R13 proved any
//      narrower dtype loses on decode VALU; 64-thr 2-node aggregates with
//      blockIdx-uniform scalar metadata; standalone 4-VGPR edge_pass).
//      CSR path tightened: scan2 eliminated (scan3 self-computes its block
//      prefix) and selfloop fused into scan3. 16 -> 14 dispatches.
// ---------------------------------------------------------------------------

#define MASK40 ((1ull << 40) - 1)

typedef float v2f __attribute__((ext_vector_type(2)));
typedef __bf16 bf16x8 __attribute__((ext_vector_type(8)));
typedef float f32x4 __attribute__((ext_vector_type(4)));

__device__ inline unsigned f2bf(float x) {            // round-to-nearest-even
    unsigned u = __float_as_uint(x);
    return (u + 0x7FFFu + ((u >> 16) & 1u)) >> 16;
}

// one u64 atomic per edge: high 24 bits = count, low 40 = sum(ew) in 2^-24 fx.
// returned old value gives this edge's rank among same-dst edges -> slot[e].
// Standalone thin kernel (4 VGPR) -> max occupancy for atomics in flight.
__global__ void edge_pass(const int* __restrict__ dst, const float* __restrict__ ew,
                          unsigned long long* packed, unsigned short* __restrict__ slot,
                          int E) {
    int e = blockIdx.x * blockDim.x + threadIdx.x;
    if (e < E) {
        int d = dst[e];
        unsigned int fx = (unsigned int)rintf(ew[e] * 16777216.0f);
        unsigned long long old =
            atomicAdd(&packed[d], (1ull << 40) | (unsigned long long)fx);
        slot[e] = (unsigned short)(old >> 40);
    }
}

// block-local exclusive scan over L[i] = cnt[i]+1, fused with dinv.
// bsums[b] = block b's total (raw, un-prefixed).
__global__ __launch_bounds__(1024) void scan1(const unsigned long long* __restrict__ packed,
                                              float* __restrict__ dinv, int* rowp,
                                              int* bsums, int total, int N) {
    __shared__ int sh[1024];
    int i = blockIdx.x * 1024 + threadIdx.x;
    int v = 0;
    if (i < N) {
        unsigned long long p = packed[i];
        float deg = 1.0f + (float)(p & MASK40) * (1.0f / 16777216.0f);
        dinv[i] = rsqrtf(deg);
        v = (int)(p >> 40) + 1;
    }
    sh[threadIdx.x] = v;
    __syncthreads();
    for (int off = 1; off < 1024; off <<= 1) {
        int t = (threadIdx.x >= (unsigned)off) ? sh[threadIdx.x - off] : 0;
        __syncthreads();
        sh[threadIdx.x] += t;
        __syncthreads();
    }
    if (i < total) rowp[i] = sh[threadIdx.x] - v;      // exclusive, pre-offset
    if (threadIdx.x == 1023) bsums[blockIdx.x] = sh[1023];
}

// finalize rowp (adding the serially-computed bsums prefix — <=98 scalar
// loads per block, L2-hot) and emit the self-loop CSR entry in the same pass.
__global__ __launch_bounds__(1024) void scan3(int* rowp, const int* __restrict__ bsums,
                                              const float* __restrict__ dinv,
                                              int2* colval, int total, int N) {
    int off = 0;
    for (int b = 0; b < blockIdx.x; ++b) off += bsums[b];   // uniform scalar loop
    int i = blockIdx.x * 1024 + threadIdx.x;
    if (i < total) {
        int r = rowp[i] + off;
        rowp[i] = r;
        if (i < N) {
            float dv = dinv[i];
            int2 cv;
            cv.x = i;
            cv.y = __float_as_int(dv * dv);   // dinv[i] * 1.0 * dinv[i]
            colval[r] = cv;
        }
    }
}

// atomic-free scatter: one 8-B write per edge (col+val interleaved).
__global__ void scatter2(const int* __restrict__ src, const int* __restrict__ dst,
                         const float* __restrict__ ew,
                         const unsigned short* __restrict__ slot,
                         const float* __restrict__ dinv, const int* __restrict__ rowp,
                         int2* colval, int E) {
    int e = blockIdx.x * blockDim.x + threadIdx.x;
    if (e < E) {
        int s = src[e], d = dst[e];
        int idx = rowp[d] + 1 + (int)slot[e];
        int2 cv;
        cv.x = s;
        cv.y = __float_as_int(dinv[s] * ew[e] * dinv[d]);
        colval[idx] = cv;
    }
}

// start[g] = lower_bound(batch, g) for g in [0, G]; batch is sorted.
__global__ void gstart_k(const int* __restrict__ batch, int* start, int N, int G) {
    int g = blockIdx.x * blockDim.x + threadIdx.x;
    if (g <= G) {
        int lo = 0, hi = N;
        while (lo < hi) {
            int mid = (lo + hi) >> 1;
            if (batch[mid] < g) lo = mid + 1; else hi = mid;
        }
        start[g] = lo;
    }
}

// Wt[l][c*128 + p] = bf16( W_l[ kappa_l(p) ][ c ] ); kappa_1 = identity,
// kappa_{2,3,4}(p): t=p>>1,h=p&1 -> k = 16*(4*((t>>1)&1)+2*(t&1)+h) + (t>>2).
__global__ void prep_w(const float* __restrict__ Wa, const float* __restrict__ Wb,
                       const float* __restrict__ Wc, const float* __restrict__ Wd,
                       unsigned short* __restrict__ Wt) {
    const int l = blockIdx.y;
    const float* W = (l == 0) ? Wa : (l == 1) ? Wb : (l == 2) ? Wc : Wd;
    const int c = blockIdx.x, p = threadIdx.x;
    int k;
    if (l == 0) {
        k = p;
    } else {
        int t = p >> 1, h = p & 1;
        int i = t >> 2, s = (t >> 1) & 1, jj = 2 * (t & 1) + h;
        k = 16 * (4 * s + jj) + i;
    }
    float v = W[k * 128 + c];
    unsigned u = __float_as_uint(v);
    Wt[l * 16384 + c * 128 + p] = (unsigned short)((u + 0x7FFFu + ((u >> 16) & 1u)) >> 16);
}

// ---------------------------------------------------------------------------
// MFMA GEMM: C = A @ W. A: fp32 (layer 1, natural order) or packed-bf16 rows
// (kappa order). Wt: bf16 [col][k] (32 KB, L1-resident). C: fp8 rows (128 B).
// Block 256 thr = 4 waves; wave owns 16 rows x 128 cols.
// C/D: col=ct*16+li, row=q*4+reg. Epilogue: byte b=li*8+4s+j of row holds
// feat (4s+j)*16+li  (the kappa order the aggregates/pre-permuted W expect).
// ---------------------------------------------------------------------------
template <int FP32IN>
__global__ __launch_bounds__(256) void gemm_mfma(const void* __restrict__ Av,
                                                 const uint4* __restrict__ Wt,
                                                 uint2* __restrict__ C, int N) {
    const int w = threadIdx.x >> 6;
    const int lane = threadIdx.x & 63;
    const int li = lane & 15, q = lane >> 4;
    const long row_base = (long)blockIdx.x * 64 + w * 16;
    const long arow = (row_base + li < (long)N) ? row_base + li : (long)N - 1;

    f32x4 acc[8];
#pragma unroll
    for (int t = 0; t < 8; ++t) acc[t] = (f32x4){0.f, 0.f, 0.f, 0.f};

#pragma unroll
    for (int ks = 0; ks < 4; ++ks) {
        bf16x8 af;
        if (FP32IN) {
            const float* Ar = (const float*)Av + arow * 128 + ks * 32 + q * 8;
            const float4 fa = *(const float4*)Ar;
            const float4 fb = *(const float4*)(Ar + 4);
            uint4 u;
            u.x = f2bf(fa.x) | (f2bf(fa.y) << 16);
            u.y = f2bf(fa.z) | (f2bf(fa.w) << 16);
            u.z = f2bf(fb.x) | (f2bf(fb.y) << 16);
            u.w = f2bf(fb.z) | (f2bf(fb.w) << 16);
            af = __builtin_bit_cast(bf16x8, u);
        } else {
            af = __builtin_bit_cast(bf16x8,
                ((const uint4*)Av)[arow * 16 + ks * 4 + q]);
        }
#pragma unroll
        for (int ct = 0; ct < 8; ++ct) {
            const bf16x8 bf = __builtin_bit_cast(
                bf16x8, Wt[(size_t)(ct * 16 + li) * 16 + ks * 4 + q]);
            acc[ct] = __builtin_amdgcn_mfma_f32_16x16x32_bf16(af, bf, acc[ct], 0, 0, 0);
        }
    }

#pragma unroll
    for (int reg = 0; reg < 4; ++reg) {
        int d0 = __builtin_amdgcn_cvt_pk_fp8_f32(acc[0][reg], acc[1][reg], 0, false);
        d0     = __builtin_amdgcn_cvt_pk_fp8_f32(acc[2][reg], acc[3][reg], d0, true);
        int d1 = __builtin_amdgcn_cvt_pk_fp8_f32(acc[4][reg], acc[5][reg], 0, false);
        d1     = __builtin_amdgcn_cvt_pk_fp8_f32(acc[6][reg], acc[7][reg], d1, true);
        const long row = row_base + q * 4 + reg;
        uint2 o; o.x = (unsigned)d0; o.y = (unsigned)d1;
        C[row * 16 + li] = o;
    }
}

// ---------------------------------------------------------------------------
// Aggregate, 2 nodes per 64-lane wave (one wave per block -> blockIdx-derived
// indices provably uniform -> rowp/colval on the scalar pipe). Half h =
// lane>>5 handles node v0+h; lane il = lane&31 loads one uint (4 fp8 feats;
// f0 = 64*(il&1)+(il>>1), feats f0+16b). HW cvt_pk_f32_fp8 decode. w=0 past
// the short half's end. fp32 accumulate; writes packed-bf16 (kappa order).
// ---------------------------------------------------------------------------
__global__ __launch_bounds__(64) void aggregate2(const unsigned* __restrict__ t32,
                                                 const int* __restrict__ rowp,
                                                 const int2* __restrict__ colval,
                                                 const float* __restrict__ bias,
                                                 unsigned* __restrict__ out16, int n) {
    const int v0 = blockIdx.x * 2;
    const int lane = threadIdx.x;
    const int h = lane >> 5, il = lane & 31;

    const int base0 = rowp[v0];
    const int mid   = rowp[v0 + 1];
    const bool have1 = (v0 + 1) < n;
    const int end1  = have1 ? rowp[v0 + 2] : mid;
    const int len0 = mid - base0;
    const int len1 = end1 - mid;
    const int maxlen = (len0 > len1) ? len0 : len1;
    const int lenh = h ? len1 : len0;

    float a0 = 0.f, a1 = 0.f, a2 = 0.f, a3 = 0.f;
    int j = 0;
    for (; j + 4 <= maxlen; j += 4) {
#pragma unroll
        for (int k = 0; k < 4; ++k) {
            const int jj = j + k;
            const int j0 = (jj < len0) ? jj : len0 - 1;
            const int j1 = (jj < len1) ? jj : len1 - 1;
            const int2 ca = colval[base0 + j0];
            const int2 cb = colval[mid + j1];
            const int c = h ? cb.x : ca.x;
            float w = __int_as_float(h ? cb.y : ca.y);
            w = (jj < lenh) ? w : 0.f;
            const unsigned u = t32[(size_t)c * 32 + il];
            const v2f lo = __builtin_amdgcn_cvt_pk_f32_fp8((int)u, false);
            const v2f hi = __builtin_amdgcn_cvt_pk_f32_fp8((int)u, true);
            a0 = fmaf(w, lo.x, a0); a1 = fmaf(w, lo.y, a1);
            a2 = fmaf(w, hi.x, a2); a3 = fmaf(w, hi.y, a3);
        }
    }
    for (; j < maxlen; ++j) {
        const int j0 = (j < len0) ? j : len0 - 1;
        const int j1 = (j < len1) ? j : len1 - 1;
        const int2 ca = colval[base0 + j0];
        const int2 cb = colval[mid + j1];
        const int c = h ? cb.x : ca.x;
        float w = __int_as_float(h ? cb.y : ca.y);
        w = (j < lenh) ? w : 0.f;
        const unsigned u = t32[(size_t)c * 32 + il];
        const v2f lo = __builtin_amdgcn_cvt_pk_f32_fp8((int)u, false);
        const v2f hi = __builtin_amdgcn_cvt_pk_f32_fp8((int)u, true);
        a0 = fmaf(w, lo.x, a0); a1 = fmaf(w, lo.y, a1);
        a2 = fmaf(w, hi.x, a2); a3 = fmaf(w, hi.y, a3);
    }

    const int f0 = 64 * (il & 1) + (il >> 1);
    const float r0 = fmaxf(a0 + bias[f0],      0.f);
    const float r1 = fmaxf(a1 + bias[f0 + 16], 0.f);
    const float r2 = fmaxf(a2 + bias[f0 + 32], 0.f);
    const float r3 = fmaxf(a3 + bias[f0 + 48], 0.f);
    const int v = v0 + h;
    if (v < n) {
        uint2 o;
        o.x = f2bf(r0) | (f2bf(r1) << 16);
        o.y = f2bf(r2) | (f2bf(r3) << 16);
        *(uint2*)&out16[(size_t)v * 64 + il * 2] = o;
    }
}

// last layer: gather as above, dot with Wc + half-wave reduce -> sv[v] (4 B).
__global__ __launch_bounds__(64) void aggregate2_last(const unsigned* __restrict__ t32,
                                                      const int* __restrict__ rowp,
                                                      const int2* __restrict__ colval,
                                                      const float* __restrict__ bias,
                                                      const float* __restrict__ Wc,
                                                      float* __restrict__ sv, int n) {
    const int v0 = blockIdx.x * 2;
    const int lane = threadIdx.x;
    const int h = lane >> 5, il = lane & 31;

    const int base0 = rowp[v0];
    const int mid   = rowp[v0 + 1];
    const bool have1 = (v0 + 1) < n;
    const int end1  = have1 ? rowp[v0 + 2] : mid;
    const int len0 = mid - base0;
    const int len1 = end1 - mid;
    const int maxlen = (len0 > len1) ? len0 : len1;
    const int lenh = h ? len1 : len0;

    float a0 = 0.f, a1 = 0.f, a2 = 0.f, a3 = 0.f;
    int j = 0;
    for (; j + 4 <= maxlen; j += 4) {
#pragma unroll
        for (int k = 0; k < 4; ++k) {
            const int jj = j + k;
            const int j0 = (jj < len0) ? jj : len0 - 1;
            const int j1 = (jj < len1) ? jj : len1 - 1;
            const int2 ca = colval[base0 + j0];
            const int2 cb = colval[mid + j1];
            const int c = h ? cb.x : ca.x;
            float w = __int_as_float(h ? cb.y : ca.y);
            w = (jj < lenh) ? w : 0.f;
            const unsigned u = t32[(size_t)c * 32 + il];
            const v2f lo = __builtin_amdgcn_cvt_pk_f32_fp8((int)u, false);
            const v2f hi = __builtin_amdgcn_cvt_pk_f32_fp8((int)u, true);
            a0 = fmaf(w, lo.x, a0); a1 = fmaf(w, lo.y, a1);
            a2 = fmaf(w, hi.x, a2); a3 = fmaf(w, hi.y, a3);
        }
    }
    for (; j < maxlen; ++j) {
        const int j0 = (j < len0) ? j : len0 - 1;
        const int j1 = (j < len1) ? j : len1 - 1;
        const int2 ca = colval[base0 + j0];
        const int2 cb = colval[mid + j1];
        const int c = h ? cb.x : ca.x;
        float w = __int_as_float(h ? cb.y : ca.y);
        w = (j < lenh) ? w : 0.f;
        const unsigned u = t32[(size_t)c * 32 + il];
        const v2f lo = __builtin_amdgcn_cvt_pk_f32_fp8((int)u, false);
        const v2f hi = __builtin_amdgcn_cvt_pk_f32_fp8((int)u, true);
        a0 = fmaf(w, lo.x, a0); a1 = fmaf(w, lo.y, a1);
        a2 = fmaf(w, hi.x, a2); a3 = fmaf(w, hi.y, a3);
    }

    const int f0 = 64 * (il & 1) + (il >> 1);
    float p = fmaxf(a0 + bias[f0],      0.f) * Wc[f0]
            + fmaxf(a1 + bias[f0 + 16], 0.f) * Wc[f0 + 16]
            + fmaxf(a2 + bias[f0 + 32], 0.f) * Wc[f0 + 32]
            + fmaxf(a3 + bias[f0 + 48], 0.f) * Wc[f0 + 48];
#pragma unroll
    for (int off = 16; off; off >>= 1) p += __shfl_xor(p, off);  // within half
    const int v = v0 + h;
    if (il == 0 && v < n) sv[v] = p;
}

// one block per graph: mean of sv over the (contiguous) segment, sigmoid.
__global__ __launch_bounds__(256) void seg_pool(const float* __restrict__ sv,
                                                const int* __restrict__ start,
                                                const float* __restrict__ bc,
                                                float* __restrict__ out, int G) {
    __shared__ float sh[4];
    const int g = blockIdx.x;
    const int s = start[g], epos = start[g + 1];
    float acc = 0.f;
    for (int i = s + threadIdx.x; i < epos; i += 256) acc += sv[i];
#pragma unroll
    for (int off = 32; off; off >>= 1) acc += __shfl_down(acc, off);
    if ((threadIdx.x & 63) == 0) sh[threadIdx.x >> 6] = acc;
    __syncthreads();
    if (threadIdx.x == 0) {
        float sum = sh[0] + sh[1] + sh[2] + sh[3];
        float cnt = (float)(epos - s);
        float z = sum / fmaxf(cnt, 1.0f) + bc[0];
        out[g] = 1.0f / (1.0f + expf(-z));
    }
}

extern "C" void kernel_launch(void* const* d_in, const int* in_sizes, int n_in,
                              void* d_out, int out_size, void* d_ws, size_t ws_size,
                              hipStream_t stream) {
    const float* x   = (const float*)d_in[0];
    const int* ei    = (const int*)d_in[1];
    const float* ew  = (const float*)d_in[2];
    const int* batch = (const int*)d_in[3];
    const float* W1 = (const float*)d_in[4];  const float* b1 = (const float*)d_in[5];
    const float* W2 = (const float*)d_in[6];  const float* b2 = (const float*)d_in[7];
    const float* W3 = (const float*)d_in[8];  const float* b3 = (const float*)d_in[9];
    const float* W4 = (const float*)d_in[10]; const float* b4 = (const float*)d_in[11];
    const float* Wc = (const float*)d_in[12]; const float* bc = (const float*)d_in[13];

    const int N = in_sizes[0] / 128;
    const int E = in_sizes[2];
    const int G = out_size;
    const int* src = ei;
    const int* dst = ei + E;
    const int nblk = (N + 63) / 64;
    const long Npad = (long)nblk * 64;

    // workspace carve (re-poisoned each call; everything read is written below
    // or harmlessly finite-garbage in pad rows)
    char* p = (char*)d_ws;
    auto alloc = [&](size_t bytes) {
        void* q = (void*)p;
        p += (bytes + 255) & ~(size_t)255;
        return q;
    };
    unsigned long long* packed = (unsigned long long*)alloc((size_t)N * 8);
    float* dinv = (float*)alloc((size_t)N * 4);
    unsigned short* slot = (unsigned short*)alloc((size_t)E * 2);
    int* rowp   = (int*)alloc((size_t)(N + 1) * 4);
    int* bsums  = (int*)alloc(1024 * 4);
    const size_t M = (size_t)E + (size_t)N;
    int2* colval = (int2*)alloc(M * 8);
    unsigned* tbuf = (unsigned*)alloc((size_t)Npad * 32 * 4);  // fp8 GEMM out (128 B/row)
    unsigned* hbuf = (unsigned*)alloc((size_t)Npad * 64 * 4);  // bf16 activations
    unsigned short* Wt = (unsigned short*)alloc(4 * 16384 * 2); // bf16 Wt[4]
    float* sv   = (float*)alloc((size_t)N * 4);
    int* start  = (int*)alloc((size_t)(G + 1) * 4);

    const int B = 256;
    const uint4* Wt4 = (const uint4*)Wt;

    // --- graph normalization + CSR build (one atomic per edge total) ---
    hipMemsetAsync(packed, 0, (size_t)N * 8, stream);
    edge_pass<<<(E + B - 1) / B, B, 0, stream>>>(dst, ew, packed, slot, E);
    const int total = N + 1;
    const int nb = (total + 1023) / 1024;
    scan1<<<nb, 1024, 0, stream>>>(packed, dinv, rowp, bsums, total, N);
    scan3<<<nb, 1024, 0, stream>>>(rowp, bsums, dinv, colval, total, N);
    scatter2<<<(E + B - 1) / B, B, 0, stream>>>(src, dst, ew, slot, dinv, rowp,
                                                colval, E);
    gstart_k<<<(G + 1 + B - 1) / B, B, 0, stream>>>(batch, start, N, G);
    prep_w<<<dim3(128, 4), 128, 0, stream>>>(W1, W2, W3, W4, Wt);

    // --- 4 GCN layers ---
    const int agrid = (N + 1) / 2;
    gemm_mfma<1><<<nblk, B, 0, stream>>>(x,    Wt4,        (uint2*)tbuf, N);
    aggregate2<<<agrid, 64, 0, stream>>>(tbuf, rowp, colval, b1, hbuf, N);
    gemm_mfma<0><<<nblk, B, 0, stream>>>(hbuf, Wt4 + 2048, (uint2*)tbuf, N);
    aggregate2<<<agrid, 64, 0, stream>>>(tbuf, rowp, colval, b2, hbuf, N);
    gemm_mfma<0><<<nblk, B, 0, stream>>>(hbuf, Wt4 + 4096, (uint2*)tbuf, N);
    aggregate2<<<agrid, 64, 0, stream>>>(tbuf, rowp, colval, b3, hbuf, N);
    gemm_mfma<0><<<nblk, B, 0, stream>>>(hbuf, Wt4 + 6144, (uint2*)tbuf, N);
    aggregate2_last<<<agrid, 64, 0, stream>>>(tbuf, rowp, colval, b4, Wc, sv, N);

    // --- segmented mean pool (batch sorted) + sigmoid ---
    seg_pool<<<G, B, 0, stream>>>(sv, start, bc, (float*)d_out, G);
}